// Round 5
// baseline (258.591 us; speedup 1.0000x reference)
//
#include <hip/hip_runtime.h>
#include <math.h>

// Problem constants: B=2, V=10000, N=16, CIN=128, COUT=64
#define V_CNT 10000
#define NB 16
#define TQ 64          // queries per block (fused kernel)
#define BQ_TOTAL 20000 // B*V

// ws float layout (weights only now — GEMM is fused):
//   [0, 2880)      W45T[kj][d]     (45 x 64, TRANSPOSED for s_load_dwordx16)
//   [2880, 3840)   WdP[r][k*5+c]   (20 x 48, permuted dir-weights)
//   [3840, 3900)   FN[f*3+axis]    (20 x 3 face normals)
#define WS_W45T  0
#define WS_WDP   2880
#define WS_FN    3840

__device__ __constant__ int FTC_d[20][5] = {
  {1,4,0,2,3},{2,0,1,4,3},{3,1,0,4,2},{4,2,0,3,1},{0,3,1,2,4},
  {3,2,0,4,1},{4,3,0,2,1},{0,4,1,2,3},{1,0,2,4,3},{2,1,0,4,3},
  {4,0,1,3,2},{0,1,2,3,4},{1,2,0,3,4},{2,3,0,1,4},{3,4,0,1,2},
  {1,3,0,2,4},{0,2,1,3,4},{4,1,0,3,2},{3,0,1,4,2},{2,4,0,1,3}};

// color of face f = _FTC[f][0]
constexpr int COLF[20] = {1,2,3,4,0,3,4,0,1,2,4,0,1,2,3,1,0,4,3,2};

// w9[k][j] = w19[W9MAP[k][j]]
constexpr int W9MAP[9][5] = {
  {0,1,2,2,2},{3,4,5,5,5},
  {9,10,11,12,13},{9,10,12,13,11},{9,10,13,11,12},
  {14,15,16,17,18},{14,15,17,18,16},{14,15,18,16,17},
  {6,7,8,8,8}};

__device__ __constant__ int FACES_d[20][3] = {
  {1,2,7},{1,3,7},{1,3,5},{1,4,5},{1,2,4},{2,7,8},{3,7,9},{3,5,11},{4,5,6},{2,4,10},
  {2,8,10},{7,8,9},{3,9,11},{5,6,11},{4,6,10},{0,8,10},{0,6,10},{0,6,11},{0,9,11},{0,8,9}};

#define PHI_F 1.61803398874989484820f
__device__ __constant__ float VS_d[12][3] = {
  {-1.f,PHI_F,0.f},{1.f,PHI_F,0.f},{-1.f,-PHI_F,0.f},{1.f,-PHI_F,0.f},
  {0.f,-1.f,PHI_F},{0.f,1.f,PHI_F},{0.f,-1.f,-PHI_F},{0.f,1.f,-PHI_F},
  {PHI_F,0.f,-1.f},{PHI_F,0.f,1.f},{-PHI_F,0.f,-1.f},{-PHI_F,0.f,1.f}};

__device__ __forceinline__ float fast_tanh(float x){
  float e = __expf(2.0f * x);
  return 1.0f - 2.0f * __builtin_amdgcn_rcpf(e + 1.0f);
}

#define FOR9(M)  M(0) M(1) M(2) M(3) M(4) M(5) M(6) M(7) M(8)
#define FOR16(M) M(0) M(1) M(2) M(3) M(4) M(5) M(6) M(7) M(8) M(9) M(10) M(11) M(12) M(13) M(14) M(15)

// LDS geometry
#define DE5_N_STRIDE 64            // de5s[c][n][q]: q-stride 1, n-stride 64, c-stride 1024
#define DE5_C_STRIDE (16*64)
#define PS_Q_STRIDE 231            // Ps[q][s*46 + kj], odd stride -> conflict-free
#define PS_S_STRIDE 46

// ---------------------------------------------------------------------------
// Kernel 1: weight prep. Blocks 0..63: W45T[kj][d] (transposed).
//           Block 64: WdP[r][k*5+c] permuted dir-weights + face normals.
// ---------------------------------------------------------------------------
__global__ __launch_bounds__(128) void prep_kernel(const float* __restrict__ W,
                                                   const float* __restrict__ Wdir,
                                                   float* __restrict__ ws){
  __shared__ float buf[128][20];
  __shared__ float part[19][4];
  __shared__ float w19s[19];
  int d = blockIdx.x;   // 0..64
  int c = threadIdx.x;  // 0..127

  const float* src = (d < 64) ? (W + ((size_t)d*128 + c)*19) : (Wdir + (size_t)c*19);
  #pragma unroll
  for (int tt = 0; tt < 19; ++tt) buf[c][tt] = src[tt];

  if (d == 64 && c < 20){
    float x=0.f, y=0.f, z=0.f;
    #pragma unroll
    for (int vv=0; vv<3; ++vv){
      int vi = FACES_d[c][vv];
      x += VS_d[vi][0]; y += VS_d[vi][1]; z += VS_d[vi][2];
    }
    float inv = rsqrtf(x*x + y*y + z*z);
    ws[WS_FN + c*3 + 0] = x*inv;
    ws[WS_FN + c*3 + 1] = y*inv;
    ws[WS_FN + c*3 + 2] = z*inv;
  }
  __syncthreads();

  // two-level column sum: 76 threads do 32 rows each, then 19 threads fold 4
  if (c < 76){
    int j = c >> 2, g = c & 3;
    float s = 0.f;
    for (int i = g*32; i < g*32+32; ++i) s += buf[i][j];
    part[j][g] = s;
  }
  __syncthreads();
  if (c < 19) w19s[c] = (part[c][0]+part[c][1]) + (part[c][2]+part[c][3]);
  __syncthreads();

  if (d < 64){
    if (c < 45){
      int k = c / 5, j = c % 5;
      ws[WS_W45T + c*64 + d] = w19s[W9MAP[k][j]];   // transposed
    }
  } else {
    // WdP[r][k*5+cc] = wd9[k][jinv] where FTC[r][jinv] == cc
    for (int i = c; i < 20*45; i += 128){
      int r  = i / 45;
      int kc = i - r*45;
      int k  = kc / 5, cc = kc - k*5;
      int jinv = 0;
      #pragma unroll
      for (int j = 0; j < 5; ++j) if (FTC_d[r][j] == cc) jinv = j;
      ws[WS_WDP + r*48 + kc] = w19s[W9MAP[k][jinv]];
    }
  }
}

// ---------------------------------------------------------------------------
// Fused kernel: 256 threads = 4 waves x 64 queries (lane = query).
//  Phase A: wave w computes de5 for its 4 n's, SoA [c][n][q] in LDS.
//  Phase B: wave w processes r in {5w..5w+4} sequentially. Weights WdP[r]
//           are WAVE-UNIFORM -> s_load into SGPRs (rounds 1-4 evidence: any
//           per-lane loop-invariant vector load gets rematerialized into the
//           loop by the allocator -> L1-latency-bound at 133+ us. SGPRs
//           can't be). 45 named-scalar VGPR accumulators; conflict-free LDS
//           atomics merge the 4 color contributions across waves.
//  Phase C (fused out-GEMM): thread (q=lane, dg=w) computes 16d x 5s tile:
//           out[d][q][s] = sum_kj W45T[kj][d] * Ps[q][s][kj]. W45T rows are
//           wave-uniform s_load_dwordx16. Kills old out_kernel (~90 us of
//           the same remat disease) + 36 MB psg round-trip.
// ---------------------------------------------------------------------------
__global__ __launch_bounds__(256, 2) void fold_kernel(const int*   __restrict__ nbr,
                                                      const float* __restrict__ verts,
                                                      const float* __restrict__ ws,
                                                      float* __restrict__ out){
  __shared__ float de5s[5*16*64];        // 20480 B, [c][n][q]
  __shared__ float Ps[64*PS_Q_STRIDE];   // 59136 B, [q][s*46+kj]
  const int t = threadIdx.x;
  const int lane = t & 63;
  const int w = __builtin_amdgcn_readfirstlane(t >> 6);   // wave id, provably uniform
  const int blockq0 = blockIdx.x * TQ;

  for (int i = t; i < 64*PS_Q_STRIDE; i += 256) Ps[i] = 0.f;

  const int qg = blockq0 + lane;
  const bool valid = (qg < BQ_TOTAL);

  // ---- Phase A ----
  if (valid){
    int q  = (qg >= V_CNT) ? qg - V_CNT : qg;
    int b0 = qg - q;
    const float vx = verts[qg*3+0], vy = verts[qg*3+1], vz = verts[qg*3+2];
    int4 nid = *(const int4*)(nbr + qg*NB + w*4);
    const float* fnp = ws + WS_FN;                 // uniform -> s_loads
#define NNBODY(NN, IDX) { \
    const float* nv = verts + (size_t)(b0 + (IDX))*3; \
    float dx = nv[0]-vx, dy = nv[1]-vy, dz = nv[2]-vz; \
    float dd = dx*dx + dy*dy + dz*dz; \
    float inv = (dd > 0.f) ? rsqrtf(dd) : 0.f; \
    dx *= inv; dy *= inv; dz *= inv; \
    float s0=0.f, s1=0.f, s2=0.f, s3=0.f, s4=0.f; \
    _Pragma("unroll") \
    for (int f = 0; f < 20; ++f){ \
      float x = fnp[f*3+0]*dx + fnp[f*3+1]*dy + fnp[f*3+2]*dz; \
      float th = fast_tanh(x); \
      if      (COLF[f]==0) s0 += th; \
      else if (COLF[f]==1) s1 += th; \
      else if (COLF[f]==2) s2 += th; \
      else if (COLF[f]==3) s3 += th; \
      else                 s4 += th; \
    } \
    int n = w*4 + (NN); \
    de5s[0*DE5_C_STRIDE + n*64 + lane] = s0; \
    de5s[1*DE5_C_STRIDE + n*64 + lane] = s1; \
    de5s[2*DE5_C_STRIDE + n*64 + lane] = s2; \
    de5s[3*DE5_C_STRIDE + n*64 + lane] = s3; \
    de5s[4*DE5_C_STRIDE + n*64 + lane] = s4; }
    NNBODY(0, nid.x)
    NNBODY(1, nid.y)
    NNBODY(2, nid.z)
    NNBODY(3, nid.w)
#undef NNBODY
  } else {
    #pragma unroll
    for (int nn = 0; nn < 4; ++nn){
      int n = w*4 + nn;
      #pragma unroll
      for (int cc = 0; cc < 5; ++cc) de5s[cc*DE5_C_STRIDE + n*64 + lane] = 0.f;
    }
  }
  __syncthreads();

  // ---- Phase B ----
  #pragma unroll 1
  for (int rr = 0; rr < 5; ++rr){
    const int r = w*5 + rr;                        // wave-uniform
    const int sr = FTC_d[r][0];
    int ji0=0, ji1=0, ji2=0, ji3=0, ji4=0;
    #pragma unroll
    for (int j = 0; j < 5; ++j){
      int f = FTC_d[r][j];
      if (f==0) ji0=j; else if (f==1) ji1=j; else if (f==2) ji2=j;
      else if (f==3) ji3=j; else ji4=j;
    }

    const float* wp = ws + WS_WDP + r*48;          // wave-uniform -> SGPRs
#define DECL_P(K) const float p##K##0=wp[K*5+0], p##K##1=wp[K*5+1], \
    p##K##2=wp[K*5+2], p##K##3=wp[K*5+3], p##K##4=wp[K*5+4];
    FOR9(DECL_P)
#undef DECL_P
#define DECL_A(K) float aC##K##0=0.f, aC##K##1=0.f, aC##K##2=0.f, \
    aC##K##3=0.f, aC##K##4=0.f;
    FOR9(DECL_A)
#undef DECL_A

    for (int n = 0; n < NB; ++n){
      float e0 = de5s[0*DE5_C_STRIDE + n*64 + lane];
      float e1 = de5s[1*DE5_C_STRIDE + n*64 + lane];
      float e2 = de5s[2*DE5_C_STRIDE + n*64 + lane];
      float e3 = de5s[3*DE5_C_STRIDE + n*64 + lane];
      float e4 = de5s[4*DE5_C_STRIDE + n*64 + lane];
#define KSTEP(K) { \
      float a = fmaxf(p##K##0*e0 + p##K##1*e1 + p##K##2*e2 \
                    + p##K##3*e3 + p##K##4*e4, 0.f); \
      aC##K##0 = fmaf(a, e0, aC##K##0); \
      aC##K##1 = fmaf(a, e1, aC##K##1); \
      aC##K##2 = fmaf(a, e2, aC##K##2); \
      aC##K##3 = fmaf(a, e3, aC##K##3); \
      aC##K##4 = fmaf(a, e4, aC##K##4); }
      FOR9(KSTEP)
#undef KSTEP
    }

    // Ps[q][sr][k*5 + jinv[c]] += accC[k][c]; lane-distinct addrs, odd stride
    float* base = &Ps[lane*PS_Q_STRIDE + sr*PS_S_STRIDE];
    float* bj0 = base + ji0; float* bj1 = base + ji1; float* bj2 = base + ji2;
    float* bj3 = base + ji3; float* bj4 = base + ji4;
#define KAT(K) atomicAdd(bj0 + K*5, aC##K##0); \
               atomicAdd(bj1 + K*5, aC##K##1); \
               atomicAdd(bj2 + K*5, aC##K##2); \
               atomicAdd(bj3 + K*5, aC##K##3); \
               atomicAdd(bj4 + K*5, aC##K##4);
    FOR9(KAT)
#undef KAT
  }
  __syncthreads();

  // ---- Phase C: fused out-GEMM ----
  {
    const float* pq = &Ps[lane*PS_Q_STRIDE];
#define DECL_O(D) float o##D##0=0.f,o##D##1=0.f,o##D##2=0.f,o##D##3=0.f,o##D##4=0.f;
    FOR16(DECL_O)
#undef DECL_O
    for (int kj = 0; kj < 45; ++kj){
      float b0 = pq[0*PS_S_STRIDE + kj];
      float b1 = pq[1*PS_S_STRIDE + kj];
      float b2 = pq[2*PS_S_STRIDE + kj];
      float b3 = pq[3*PS_S_STRIDE + kj];
      float b4 = pq[4*PS_S_STRIDE + kj];
      const float* wt = ws + WS_W45T + kj*64 + w*16;  // wave-uniform -> s_load_dwordx16
#define GST(D) { float wv = wt[D]; \
      o##D##0 = fmaf(wv, b0, o##D##0); \
      o##D##1 = fmaf(wv, b1, o##D##1); \
      o##D##2 = fmaf(wv, b2, o##D##2); \
      o##D##3 = fmaf(wv, b3, o##D##3); \
      o##D##4 = fmaf(wv, b4, o##D##4); }
      FOR16(GST)
#undef GST
    }
    if (valid){
      int q = (qg >= V_CNT) ? qg - V_CNT : qg;
      int b = (qg >= V_CNT) ? 1 : 0;
      float* ob = out + (size_t)b*3200000 + (size_t)(w*16)*50000 + (size_t)q*5;
#define OST(D) { float* o_ = ob + (size_t)(D)*50000; \
      o_[0]=o##D##0; o_[1]=o##D##1; o_[2]=o##D##2; o_[3]=o##D##3; o_[4]=o##D##4; }
      FOR16(OST)
#undef OST
    }
  }
}

extern "C" void kernel_launch(void* const* d_in, const int* in_sizes, int n_in,
                              void* d_out, int out_size, void* d_ws, size_t ws_size,
                              hipStream_t stream){
  const int*   nbr   = (const int*)d_in[0];
  const float* verts = (const float*)d_in[1];
  const float* W     = (const float*)d_in[2];
  const float* Wdir  = (const float*)d_in[3];
  float* out = (float*)d_out;
  float* ws  = (float*)d_ws;

  hipLaunchKernelGGL(prep_kernel, dim3(65), dim3(128), 0, stream, W, Wdir, ws);
  hipLaunchKernelGGL(fold_kernel, dim3((BQ_TOTAL + TQ - 1)/TQ), dim3(256), 0, stream,
                     nbr, verts, ws, out);
}